// Round 12
// baseline (195.726 us; speedup 1.0000x reference)
//
#include <hip/hip_runtime.h>
#include <math.h>

// Disable FP contraction file-wide so every rounding step is the one we wrote;
// fmas are explicit (packed fma asm) matching the XLA/Eigen dot chain.
#pragma clang fp contract(off)

#define VOCAB 4096
#define NPTS  32768          // 4 * 8192
#define NELEM 98304          // NPTS * 3
#define BLOCK 1024
#define NWAVE 16                     // waves per block
#define CPW   (VOCAB / NWAVE)        // 256 codes scanned per wave
#define PAIRS_PW (CPW / 2)           // 128 code-pairs per wave
#define JITER (PAIRS_PW / 2)         // 64 j-iters (1 LDS pair + 1 GLB pair)
#define PPL   2                      // points per lane
#define PTS_PER_BLOCK (64 * PPL)     // 128 points per block -> 256 blocks

typedef float v2f __attribute__((ext_vector_type(2)));

// ---------------------------------------------------------------------------
// Kernel 0: pack codebook in PAIR layout (negated, pre-doubled, + esq) AND
// zero the counts/sums/sse workspace (memset folded in).
//   pc[2m]   = (-2e0_k, -2e0_k1, -2e1_k, -2e1_k1)    (codes k=2m, k1=2m+1)
//   pc[2m+1] = (-2e2_k, -2e2_k1,  esq_k,  esq_k1)
// Negation and x2 are exact; IEEE rounding is sign-symmetric, so the packed
// mul/fma chain on these values is bit-exactly -2*dot of the reference chain.
// esq keeps the reference association (e0*e0 + e1*e1) + e2*e2.
// ---------------------------------------------------------------------------
__global__ __launch_bounds__(1024) void vq_prep(
    const float* __restrict__ embed, float4* __restrict__ pc,
    float* __restrict__ wz)
{
  const int gid = blockIdx.x * 1024 + threadIdx.x;   // [0, 2048)
  #pragma unroll
  for (int i = 0; i < 8; ++i) wz[gid * 8 + i] = 0.0f;
  if (gid == 0) wz[16384] = 0.0f;

  const int m = gid;                 // pair id
  const int c0 = 2 * m, c1 = 2 * m + 1;
  float a0 = embed[3 * c0 + 0], a1 = embed[3 * c0 + 1], a2 = embed[3 * c0 + 2];
  float b0 = embed[3 * c1 + 0], b1 = embed[3 * c1 + 1], b2 = embed[3 * c1 + 2];
  float esqa = (a0 * a0 + a1 * a1) + a2 * a2;
  float esqb = (b0 * b0 + b1 * b1) + b2 * b2;
  pc[2 * m + 0] = make_float4(-(a0 + a0), -(b0 + b0), -(a1 + a1), -(b1 + b1));
  pc[2 * m + 1] = make_float4(-(a2 + a2), -(b2 + b2), esqa, esqb);
}

// ---------------------------------------------------------------------------
// Kernel 1: nearest-code assignment + quant_st + idx + scatter + SSE.
//
// r11 post-mortem: compiler dismantled the named-slot prefetch (VGPR=64) and
// the per-op asm + vector 64-bit addressing emitted ~90 VALU/j-iter vs ~50
// source ops. This round strips the loop to its floor:
//  - FULL UNROLL (JITER=64): LDS reads via base + 16-bit imm offset
//    (max 2032), global reads via base + 13-bit imm offset (max 4048 < 4096):
//    ZERO per-iteration address VALU, zero loop overhead.
//  - Track winning ITERATION jj (inline-constant range 0..63) per stream via
//    cndmask -- no index-literal v_movs. Code idx rebuilt in the epilogue:
//    bi = 2*mbase + 4*jj + stream. Ascending jj + strict < keeps first-min;
//    cross-stream/wave lexicographic (d, idx) merge as verified (absmax 0).
//  - One asm block per 5-op packed chain (same op sequence as r10/r11 =>
//    bit-identical); tracking in plain C for scheduler freedom.
// Floor: 44 VALU/j-iter x 64 x 4 waves/SIMD x 2cyc = 9.4us VALU; LDS-return
// 10.2us; VMEM-return ~7-14us. Wall should approach max(), not sum().
// ---------------------------------------------------------------------------
#define CHAIN(T, W0, W1, S)                                                   \
  {                                                                           \
    v2f A  = {(W0).x, (W0).y};                                                \
    v2f Bv = {(W0).z, (W0).w};                                                \
    v2f Cv = {(W1).x, (W1).y};                                                \
    v2f Sv = {(W1).z, (W1).w};                                                \
    asm("v_pk_mul_f32 %0, %1, %5\n\t"                                         \
        "v_pk_fma_f32 %0, %2, %6, %0\n\t"                                     \
        "v_pk_fma_f32 %0, %3, %7, %0\n\t"                                     \
        "v_pk_add_f32 %0, %4, %0\n\t"                                         \
        "v_pk_add_f32 %0, %8, %0"                                             \
        : "=&v"(T)                                                            \
        : "v"(xp0[S]), "v"(xp1[S]), "v"(xp2[S]), "v"(xpq[S]),                 \
          "v"(A), "v"(Bv), "v"(Cv), "v"(Sv));                                 \
  }

__global__ __launch_bounds__(BLOCK, 4) void vq_assign(
    const float* __restrict__ feats, const float* __restrict__ embed,
    const float4* __restrict__ gpc,
    float* __restrict__ out_quant, float* __restrict__ out_idx,
    float* __restrict__ counts, float* __restrict__ sums,
    float* __restrict__ sse)
{
  extern __shared__ float4 lpc[];          // 2048 float4 = 32 KiB

  const int tid  = threadIdx.x;
  const int lane = tid & 63;
  const int wv   = tid >> 6;

  // Stage even pairs: lpc[2ep + w] = gpc[4ep + w].
  #pragma unroll
  for (int c = tid; c < 2048; c += BLOCK)
    lpc[c] = gpc[4 * (c >> 1) + (c & 1)];
  __syncthreads();

  // Lane owns points pbase+lane (slot 0) and pbase+64+lane (slot 1).
  const int pbase = blockIdx.x * PTS_PER_BLOCK;
  v2f xp0[PPL], xp1[PPL], xp2[PPL], xpq[PPL];
  #pragma unroll
  for (int s = 0; s < PPL; ++s) {
    const int p = pbase + s * 64 + lane;
    float x0 = feats[3 * p + 0];
    float x1 = feats[3 * p + 1];
    float x2 = feats[3 * p + 2];
    float xsq = (x0 * x0 + x1 * x1) + x2 * x2;
    xp0[s] = (v2f){x0, x0}; xp1[s] = (v2f){x1, x1};
    xp2[s] = (v2f){x2, x2}; xpq[s] = (v2f){xsq, xsq};
  }

  // 4 streams per point: 0=LDS-lo, 1=LDS-hi, 2=GLB-lo, 3=GLB-hi.
  // Track (best d, winning jj); jj in [0,64) = inline-constant range.
  float bst[4][PPL];
  int   jjw[4][PPL];
  #pragma unroll
  for (int st = 0; st < 4; ++st)
    #pragma unroll
    for (int s = 0; s < PPL; ++s) { bst[st][s] = INFINITY; jjw[st][s] = 0; }

  const int mbase = wv * PAIRS_PW;         // wave's pair range base
  // LDS base: wave's even-pair block (byte = mbase*16), imm offsets 0..2032.
  const float4* lbase = lpc + mbase;
  // Opaque VGPR zero keeps the global stream on the vector L1/L2 path
  // (prevents s_load scalarization -- the r5 K$ disaster).
  int vz;
  asm volatile("v_mov_b32 %0, 0" : "=v"(vz));
  // Global base: first odd pair of the range (float4 index 2*mbase+2),
  // imm offsets 64*jj + {0,16} <= 4048 < 4096 (13-bit signed field).
  const float4* gbase = gpc + 2 * mbase + 2 + vz;

  #pragma unroll
  for (int jj = 0; jj < JITER; ++jj) {
    float4 L0 = lbase[2 * jj];             // ds_read_b128  offset:32jj
    float4 L1 = lbase[2 * jj + 1];         // ds_read_b128  offset:32jj+16
    float4 G0 = gbase[4 * jj];             // global dwordx4 offset:64jj
    float4 G1 = gbase[4 * jj + 1];         // global dwordx4 offset:64jj+16
    #pragma unroll
    for (int s = 0; s < PPL; ++s) {
      v2f tL, tG;
      CHAIN(tL, L0, L1, s);
      CHAIN(tG, G0, G1, s);
      if (tL.x < bst[0][s]) { bst[0][s] = tL.x; jjw[0][s] = jj; }
      if (tL.y < bst[1][s]) { bst[1][s] = tL.y; jjw[1][s] = jj; }
      if (tG.x < bst[2][s]) { bst[2][s] = tG.x; jjw[2][s] = jj; }
      if (tG.y < bst[3][s]) { bst[3][s] = tG.y; jjw[3][s] = jj; }
    }
  }

  // merge the 4 streams per point (lexicographic (d, code-idx))
  __syncthreads();                         // codebook dead -> overlay OK
  float* dbuf = (float*)lpc;               // [NWAVE][PPL][64] floats (8 KiB)
  int*   ibuf = (int*)lpc + NWAVE * PPL * 64;
  #pragma unroll
  for (int s = 0; s < PPL; ++s) {
    float b  = bst[0][s];
    int   bi = 2 * mbase + 4 * jjw[0][s];  // stream 0 -> code offset 0
    #pragma unroll
    for (int st = 1; st < 4; ++st) {
      int cand = 2 * mbase + 4 * jjw[st][s] + st;
      if (bst[st][s] < b || (bst[st][s] == b && cand < bi)) {
        b = bst[st][s]; bi = cand;
      }
    }
    dbuf[(wv * PPL + s) * 64 + lane] = b;
    ibuf[(wv * PPL + s) * 64 + lane] = bi;
  }
  __syncthreads();

  if (wv == 0) {
    #pragma unroll
    for (int s = 0; s < PPL; ++s) {
      float b  = dbuf[s * 64 + lane];
      int   bi = ibuf[s * 64 + lane];
      #pragma unroll
      for (int w = 1; w < NWAVE; ++w) {
        float od = dbuf[(w * PPL + s) * 64 + lane];
        int   oi = ibuf[(w * PPL + s) * 64 + lane];
        // lexicographic (d, idx): wave ranges ascending => first-min
        if (od < b || (od == b && oi < bi)) { b = od; bi = oi; }
      }

      const int p = pbase + s * 64 + lane;
      // winning code values straight from embed: bit-exact originals
      const float q0 = embed[3 * bi + 0];
      const float q1 = embed[3 * bi + 1];
      const float q2 = embed[3 * bi + 2];
      const float x0 = xp0[s].x, x1 = xp1[s].x, x2 = xp2[s].x;

      // quant_st = feats + (quant - feats), exactly as the reference does
      out_quant[3 * p + 0] = x0 + (q0 - x0);
      out_quant[3 * p + 1] = x1 + (q1 - x1);
      out_quant[3 * p + 2] = x2 + (q2 - x2);
      out_idx[p] = (float)bi;

      atomicAdd(&counts[bi], 1.0f);
      atomicAdd(&sums[3 * bi + 0], x0);
      atomicAdd(&sums[3 * bi + 1], x1);
      atomicAdd(&sums[3 * bi + 2], x2);

      float d0 = q0 - x0, d1 = q1 - x1, d2 = q2 - x2;
      float l = (d0 * d0 + d1 * d1) + d2 * d2;
      #pragma unroll
      for (int m = 1; m <= 32; m <<= 1) l += __shfl_xor(l, m, 64);
      if (lane == 0) atomicAdd(sse, l);
    }
  }
}

// ---------------------------------------------------------------------------
// Kernel 2: EMA update, global n-reduction, normalized embed, loss finalize.
// (unchanged from the verified rounds)
// ---------------------------------------------------------------------------
__global__ __launch_bounds__(1024) void vq_ema(
    const float* __restrict__ counts, const float* __restrict__ sums,
    const float* __restrict__ sse,
    const float* __restrict__ ema_cs, const float* __restrict__ ema_w,
    float* __restrict__ out_loss, float* __restrict__ out_ncs,
    float* __restrict__ out_nw, float* __restrict__ out_nemb)
{
  __shared__ float part[16];
  const int tid = threadIdx.x;
  const float DEC = 0.99f;
  const float OMD = (float)(1.0 - 0.99);
  const float EPS = 1e-5f;

  float ncs[4];
  float nw[12];
  float nsum = 0.0f;

  #pragma unroll
  for (int k = 0; k < 4; ++k) {
    int v = k * 1024 + tid;
    float t = DEC * ema_cs[v] + OMD * counts[v];
    ncs[k] = t;
    out_ncs[v] = t;
    nsum += t;
    #pragma unroll
    for (int d = 0; d < 3; ++d) {
      float w = DEC * ema_w[3 * v + d] + OMD * sums[3 * v + d];
      nw[3 * k + d] = w;
      out_nw[3 * v + d] = w;
    }
  }

  #pragma unroll
  for (int m = 1; m <= 32; m <<= 1) nsum += __shfl_xor(nsum, m, 64);
  if ((tid & 63) == 0) part[tid >> 6] = nsum;
  __syncthreads();

  float n = 0.0f;
  #pragma unroll
  for (int i = 0; i < 16; ++i) n += part[i];
  const float denom = n + (float)VOCAB * EPS;

  #pragma unroll
  for (int k = 0; k < 4; ++k) {
    int v = k * 1024 + tid;
    float cs = (ncs[k] + EPS) / denom * n;
    #pragma unroll
    for (int d = 0; d < 3; ++d)
      out_nemb[3 * v + d] = nw[3 * k + d] / cs;
  }

  if (tid == 0) {
    float m = sse[0] / (float)NELEM;
    out_loss[0] = m + 0.25f * m;   // mean((q-f)^2) + 0.25*mean((f-q)^2)
  }
}

// ---------------------------------------------------------------------------
extern "C" void kernel_launch(void* const* d_in, const int* in_sizes, int n_in,
                              void* d_out, int out_size, void* d_ws, size_t ws_size,
                              hipStream_t stream) {
  const float* feats  = (const float*)d_in[0];   // (4,8192,3)
  const float* embed  = (const float*)d_in[1];   // (4096,3)
  const float* ema_cs = (const float*)d_in[2];   // (4096,)
  const float* ema_w  = (const float*)d_in[3];   // (4096,3)

  float* out      = (float*)d_out;
  float* o_quant  = out;                       // 98304
  float* o_idx    = out + 98304;               // 32768
  float* o_loss   = out + 131072;              // 1
  float* o_ncs    = out + 131073;              // 4096
  float* o_nw     = out + 135169;              // 12288
  float* o_nemb   = out + 147457;              // 12288

  float*  ws_f      = (float*)d_ws;
  float*  ws_counts = ws_f;                    // 4096
  float*  ws_sums   = ws_f + 4096;             // 12288
  float*  ws_sse    = ws_f + 16384;            // 1 (+3 pad)
  float4* ws_pc     = (float4*)(ws_f + 16388); // 4096 float4 (byte 65552, 16B-aligned)

  vq_prep<<<2, 1024, 0, stream>>>(embed, ws_pc, ws_f);

  vq_assign<<<NPTS / PTS_PER_BLOCK, BLOCK, 2048 * sizeof(float4), stream>>>(
      feats, embed, ws_pc, o_quant, o_idx, ws_counts, ws_sums, ws_sse);

  vq_ema<<<1, 1024, 0, stream>>>(
      ws_counts, ws_sums, ws_sse, ema_cs, ema_w,
      o_loss, o_ncs, o_nw, o_nemb);
}

// Round 13
// 63.613 us; speedup vs baseline: 3.0768x; 3.0768x over previous
//
#include <hip/hip_runtime.h>
#include <math.h>

// Disable FP contraction file-wide so every rounding step is the one we wrote.
#pragma clang fp contract(off)

#define VOCAB 4096
#define NPTS  32768          // 4 * 8192
#define NELEM 98304          // NPTS * 3
#define BLOCK 256
#define GRID  512            // 64 points per block

typedef float v2f __attribute__((ext_vector_type(2)));

static __device__ __forceinline__ v2f fma2(v2f a, v2f b, v2f c) {
#if __has_builtin(__builtin_elementwise_fma)
  return __builtin_elementwise_fma(a, b, c);    // llvm.fma.v2f32 -> v_pk_fma_f32
#else
  v2f r; r.x = fmaf(a.x, b.x, c.x); r.y = fmaf(a.y, b.y, c.y); return r;
#endif
}

// ---------------------------------------------------------------------------
// Kernel 0: pack codebook as float4 (-2e0, -2e1, -2e2, esq) and zero the
// counts/sums/sse workspace. Negation and x2 are exact; IEEE rounding is
// sign-symmetric, so an fma chain on these gives bit-exactly -2*dot of the
// reference chain (verified absmax 0 in r10-r12). esq keeps the reference
// association (e0*e0 + e1*e1) + e2*e2.
// ---------------------------------------------------------------------------
__global__ __launch_bounds__(256) void vq_prep(
    const float* __restrict__ embed, float4* __restrict__ pc4,
    float* __restrict__ wz)
{
  const int c = blockIdx.x * 256 + threadIdx.x;   // [0, 4096)
  #pragma unroll
  for (int i = 0; i < 4; ++i) wz[4 * c + i] = 0.0f;   // counts+sums = 16384
  if (c == 0) wz[16384] = 0.0f;                       // sse

  float e0 = embed[3 * c + 0];
  float e1 = embed[3 * c + 1];
  float e2 = embed[3 * c + 2];
  float esq = (e0 * e0 + e1 * e1) + e2 * e2;
  pc4[c] = make_float4(-(e0 + e0), -(e1 + e1), -(e2 + e2), esq);
}

// ---------------------------------------------------------------------------
// Kernel 1: nearest-code assignment + quant_st + idx + scatter + SSE.
//
// Structure (r13): 16-lane groups own 4 points each; lane gl scans codes
// ci = 16k + gl DIRECTLY FROM GLOBAL (L1/L2-resident packed array) -- each
// wave-read is 256 B coalesced and delivers 64 DISTINCT code words (vs the
// r4-r12 broadcast structures, where 64 lanes received the same 16 B: 64x
// return-path waste -- the invariant behind the 40us wall). No LDS, no
// barriers; the only cross-lane step is a 4-hop shuffle butterfly inside
// each 16-lane group.
//
// Math: plain-C v2f packed ops, 2 points per instruction (p01 / p23 pairs);
// chain = ((x0*-2e0) fma x1*-2e1 fma x2*-2e2) + xsq) + esq, bit-identical
// per half to the verified reference expression. Scan ascending k + strict
// < keeps first occurrence per lane; cross-lane lexicographic (d, idx)
// merge preserves argmin first-min semantics (r2-verified scheme).
// ---------------------------------------------------------------------------
__global__ __launch_bounds__(BLOCK, 2) void vq_assign(
    const float* __restrict__ feats, const float* __restrict__ embed,
    const float4* __restrict__ pc4,
    float* __restrict__ out_quant, float* __restrict__ out_idx,
    float* __restrict__ counts, float* __restrict__ sums,
    float* __restrict__ sse)
{
  const int tid  = threadIdx.x;
  const int lane = tid & 63;
  const int wv   = tid >> 6;
  const int g    = lane >> 4;          // group within wave (0..3)
  const int gl   = lane & 15;          // lane within group
  const int ggid = (blockIdx.x * 4 + wv) * 4 + g;   // global group id
  const int pbase = ggid * 4;          // 4 consecutive points per group

  // Load the group's 4 points (48 B, 16B-aligned; same addr across the 16
  // lanes -> L1 broadcast). p0=(v0.x,y,z) p1=(v0.w,v1.x,y) p2=(v1.z,w,v2.x)
  // p3=(v2.y,z,w).
  const float4* fp = (const float4*)(feats + 3 * pbase);
  const float4 v0 = fp[0], v1 = fp[1], v2 = fp[2];

  // xsq per point, reference association (x0*x0 + x1*x1) + x2*x2.
  const float s0 = (v0.x * v0.x + v0.y * v0.y) + v0.z * v0.z;
  const float s1 = (v0.w * v0.w + v1.x * v1.x) + v1.y * v1.y;
  const float s2 = (v1.z * v1.z + v1.w * v1.w) + v2.x * v2.x;
  const float s3 = (v2.y * v2.y + v2.z * v2.z) + v2.w * v2.w;

  // packed point pairs {p0,p1} and {p2,p3}
  const v2f xa0 = {v0.x, v0.w}, xa1 = {v0.y, v1.x}, xa2 = {v0.z, v1.y};
  const v2f xb0 = {v1.z, v2.y}, xb1 = {v1.w, v2.z}, xb2 = {v2.x, v2.w};
  const v2f xqa = {s0, s1},     xqb = {s2, s3};

  float bd0 = INFINITY, bd1 = INFINITY, bd2 = INFINITY, bd3 = INFINITY;
  int   bk0 = 0, bk1 = 0, bk2 = 0, bk3 = 0;

  const float4* cp = pc4 + gl;         // lane's code stream: ci = 16k + gl

  #pragma unroll 8
  for (int k = 0; k < VOCAB / 16; ++k) {
    const float4 E = cp[16 * k];       // coalesced 256 B per wave, L1/L2
    const v2f e0 = {E.x, E.x}, e1 = {E.y, E.y}, e2 = {E.z, E.z};
    const v2f es = {E.w, E.w};

    v2f ta = xa0 * e0;                 // v_pk_mul_f32
    ta = fma2(xa1, e1, ta);            // v_pk_fma_f32
    ta = fma2(xa2, e2, ta);
    ta = ta + xqa;                     // (-2dot) + xsq == xsq - 2dot
    ta = ta + es;                      // ... + esq  (reference association)

    v2f tb = xb0 * e0;
    tb = fma2(xb1, e1, tb);
    tb = fma2(xb2, e2, tb);
    tb = tb + xqb;
    tb = tb + es;

    // strict < : first occurrence within the ascending-k stream
    if (ta.x < bd0) { bd0 = ta.x; bk0 = k; }
    if (ta.y < bd1) { bd1 = ta.y; bk1 = k; }
    if (tb.x < bd2) { bd2 = tb.x; bk2 = k; }
    if (tb.y < bd3) { bd3 = tb.y; bk3 = k; }
  }

  // code index per lane, then lexicographic (d, idx) butterfly over the
  // 16-lane group (xor masks 1..8 stay inside the group).
  float bd[4] = {bd0, bd1, bd2, bd3};
  int   bi[4] = {16 * bk0 + gl, 16 * bk1 + gl, 16 * bk2 + gl, 16 * bk3 + gl};
  #pragma unroll
  for (int m = 1; m <= 8; m <<= 1) {
    #pragma unroll
    for (int j = 0; j < 4; ++j) {
      float od = __shfl_xor(bd[j], m, 64);
      int   oi = __shfl_xor(bi[j], m, 64);
      if (od < bd[j] || (od == bd[j] && oi < bi[j])) { bd[j] = od; bi[j] = oi; }
    }
  }

  // epilogue: lanes gl=0..3 each own one point
  float l = 0.0f;
  if (gl < 4) {
    float b = bd[0];
    int   bidx = bi[0];
    float x0 = v0.x, x1 = v0.y, x2 = v0.z;
    #pragma unroll
    for (int j = 1; j < 4; ++j) {
      if (gl == j) {
        b = bd[j]; bidx = bi[j];
        x0 = (j == 1) ? v0.w : ((j == 2) ? v1.z : v2.y);
        x1 = (j == 1) ? v1.x : ((j == 2) ? v1.w : v2.z);
        x2 = (j == 1) ? v1.y : ((j == 2) ? v2.x : v2.w);
      }
    }
    (void)b;
    const int p = pbase + gl;

    // winning code values straight from embed: bit-exact originals
    const float q0 = embed[3 * bidx + 0];
    const float q1 = embed[3 * bidx + 1];
    const float q2 = embed[3 * bidx + 2];

    // quant_st = feats + (quant - feats), exactly as the reference does
    out_quant[3 * p + 0] = x0 + (q0 - x0);
    out_quant[3 * p + 1] = x1 + (q1 - x1);
    out_quant[3 * p + 2] = x2 + (q2 - x2);
    out_idx[p] = (float)bidx;

    atomicAdd(&counts[bidx], 1.0f);
    atomicAdd(&sums[3 * bidx + 0], x0);
    atomicAdd(&sums[3 * bidx + 1], x1);
    atomicAdd(&sums[3 * bidx + 2], x2);

    float d0 = q0 - x0, d1 = q1 - x1, d2 = q2 - x2;
    l = (d0 * d0 + d1 * d1) + d2 * d2;
  }

  // wave-reduce SSE partials (16 contributing lanes), 1 atomic per wave
  #pragma unroll
  for (int m = 1; m <= 32; m <<= 1) l += __shfl_xor(l, m, 64);
  if (lane == 0) atomicAdd(sse, l);
}

// ---------------------------------------------------------------------------
// Kernel 2: EMA update, global n-reduction, normalized embed, loss finalize.
// (unchanged from the verified rounds)
// ---------------------------------------------------------------------------
__global__ __launch_bounds__(1024) void vq_ema(
    const float* __restrict__ counts, const float* __restrict__ sums,
    const float* __restrict__ sse,
    const float* __restrict__ ema_cs, const float* __restrict__ ema_w,
    float* __restrict__ out_loss, float* __restrict__ out_ncs,
    float* __restrict__ out_nw, float* __restrict__ out_nemb)
{
  __shared__ float part[16];
  const int tid = threadIdx.x;
  const float DEC = 0.99f;
  const float OMD = (float)(1.0 - 0.99);
  const float EPS = 1e-5f;

  float ncs[4];
  float nw[12];
  float nsum = 0.0f;

  #pragma unroll
  for (int k = 0; k < 4; ++k) {
    int v = k * 1024 + tid;
    float t = DEC * ema_cs[v] + OMD * counts[v];
    ncs[k] = t;
    out_ncs[v] = t;
    nsum += t;
    #pragma unroll
    for (int d = 0; d < 3; ++d) {
      float w = DEC * ema_w[3 * v + d] + OMD * sums[3 * v + d];
      nw[3 * k + d] = w;
      out_nw[3 * v + d] = w;
    }
  }

  #pragma unroll
  for (int m = 1; m <= 32; m <<= 1) nsum += __shfl_xor(nsum, m, 64);
  if ((tid & 63) == 0) part[tid >> 6] = nsum;
  __syncthreads();

  float n = 0.0f;
  #pragma unroll
  for (int i = 0; i < 16; ++i) n += part[i];
  const float denom = n + (float)VOCAB * EPS;

  #pragma unroll
  for (int k = 0; k < 4; ++k) {
    int v = k * 1024 + tid;
    float cs = (ncs[k] + EPS) / denom * n;
    #pragma unroll
    for (int d = 0; d < 3; ++d)
      out_nemb[3 * v + d] = nw[3 * k + d] / cs;
  }

  if (tid == 0) {
    float m = sse[0] / (float)NELEM;
    out_loss[0] = m + 0.25f * m;   // mean((q-f)^2) + 0.25*mean((f-q)^2)
  }
}

// ---------------------------------------------------------------------------
extern "C" void kernel_launch(void* const* d_in, const int* in_sizes, int n_in,
                              void* d_out, int out_size, void* d_ws, size_t ws_size,
                              hipStream_t stream) {
  const float* feats  = (const float*)d_in[0];   // (4,8192,3)
  const float* embed  = (const float*)d_in[1];   // (4096,3)
  const float* ema_cs = (const float*)d_in[2];   // (4096,)
  const float* ema_w  = (const float*)d_in[3];   // (4096,3)

  float* out      = (float*)d_out;
  float* o_quant  = out;                       // 98304
  float* o_idx    = out + 98304;               // 32768
  float* o_loss   = out + 131072;              // 1
  float* o_ncs    = out + 131073;              // 4096
  float* o_nw     = out + 135169;              // 12288
  float* o_nemb   = out + 147457;              // 12288

  float*  ws_f      = (float*)d_ws;
  float*  ws_counts = ws_f;                    // 4096
  float*  ws_sums   = ws_f + 4096;             // 12288
  float*  ws_sse    = ws_f + 16384;            // 1 (+3 pad)
  float4* ws_pc4    = (float4*)(ws_f + 16388); // 4096 float4 (byte 65552, 16B-aligned)

  vq_prep<<<VOCAB / 256, 256, 0, stream>>>(embed, ws_pc4, ws_f);

  vq_assign<<<GRID, BLOCK, 0, stream>>>(
      feats, embed, ws_pc4, o_quant, o_idx, ws_counts, ws_sums, ws_sse);

  vq_ema<<<1, 1024, 0, stream>>>(
      ws_counts, ws_sums, ws_sse, ema_cs, ema_w,
      o_loss, o_ncs, o_nw, o_nemb);
}